// Round 2
// baseline (112.208 us; speedup 1.0000x reference)
//
#include <hip/hip_runtime.h>
#include <hip/hip_bf16.h>

// B=4, Q=K=512, D=512, H=256
#define HH 256
#define DD 512
#define MM 2048                       // B*Q == B*K flattened rows
#define CSCALE 2.8853900817779268f    // 2*log2(e), folded into W (linear)

typedef __bf16 bf16x8 __attribute__((ext_vector_type(8)));
typedef float floatx4 __attribute__((ext_vector_type(4)));

// ---------------------------------------------------------------------------
// prep (R12): W + wv only — X conversion folded into proj (f32 direct load).
//   blocks 0..255: transpose+scale Wq,Wk -> Wt[2][256][512] bf16
//   block 256:     wv2 = -2*wv, sumW = sum(wv)
// ---------------------------------------------------------------------------
__global__ __launch_bounds__(256) void prep_kernel(
    const float* __restrict__ Wq, const float* __restrict__ Wk,
    const float* __restrict__ wv,
    __bf16* __restrict__ Wt, float* __restrict__ wv2, float* __restrict__ sumWp)
{
  const int bx = blockIdx.x;
  if (bx < 256) {
    const int mat  = bx >> 7;
    const int tile = bx & 127;
    const int kt = tile & 15;    // 512/32 k-tiles
    const int nt = tile >> 4;    // 256/32 n-tiles
    const float* __restrict__ W = mat ? Wk : Wq;
    __bf16* __restrict__ Wo = Wt + (size_t)mat * HH * DD;
    __shared__ float lds[32][33];
    const int i = threadIdx.x >> 5;   // 0..7
    const int j = threadIdx.x & 31;   // 0..31
    const int k0 = kt * 32, n0 = nt * 32;
#pragma unroll
    for (int p = 0; p < 4; ++p)
      lds[i + p * 8][j] = W[(k0 + i + p * 8) * HH + n0 + j];
    __syncthreads();
#pragma unroll
    for (int p = 0; p < 4; ++p) {
      const int n = i + p * 8;
      Wo[(n0 + n) * DD + k0 + j] = (__bf16)(lds[j][n] * CSCALE);
    }
  } else {
    __shared__ float red[256];
    const int t = threadIdx.x;
    float w = wv[t];
    wv2[t] = -2.0f * w;
    red[t] = w;
    __syncthreads();
    for (int s = 128; s > 0; s >>= 1) {
      if (t < s) red[t] += red[t + s];
      __syncthreads();
    }
    if (t == 0) *sumWp = red[0];
  }
}

// ---------------------------------------------------------------------------
// proj (R12): A-operand loaded f32 DIRECTLY from queries/keys (no Xbf
// staging pass): 2x dwordx4 + compiler-emitted v_cvt_pk_bf16_f32 per
// fragment. Same RNE rounding as the old prep conversion -> numerics
// identical. A-reuse is XCD-local for free: linear wgid = x+64y+512z,
// XCD = x%8, so all 16 (y,z) blocks of an m-tile share one XCD's L2.
// Epilogue unchanged:
//   z==0: queries -> eq = exp2(qc) f32  [2048][256]
//   z==1: keys    -> ek = exp2(kc) f32  [m/16][hq(64)][m%16][4]
// Fragment layouts (HW-verified rounds 1-9):
//   A: lane A[m=lane&15][k=(lane>>4)*8+j]; B: B[k=(lane>>4)*8+j][n=lane&15]
//   D: reg i -> row=(lane>>4)*4+i, col=lane&15
// ---------------------------------------------------------------------------
__global__ __launch_bounds__(256, 4) void proj_kernel(
    const float* __restrict__ queries, const float* __restrict__ keys,
    const __bf16* __restrict__ Wt,
    float* __restrict__ eqp, float* __restrict__ ekf)
{
  const int w    = threadIdx.x >> 6;
  const int lane = threadIdx.x & 63;
  const int quad = lane >> 4;
  const int r    = lane & 15;
  const int tw = w & 1;        // which 16-row tile
  const int ks = w >> 1;       // which K half
  const bool is_k = (blockIdx.z != 0);
  const float* __restrict__ X  = is_k ? keys : queries;
  const __bf16* __restrict__ Wb = Wt + (is_k ? (size_t)HH * DD : 0);

  const int m0 = blockIdx.x * 32 + tw * 16;
  const int n0 = blockIdx.y * 32;

  floatx4 acc0 = {0.f, 0.f, 0.f, 0.f};
  floatx4 acc1 = {0.f, 0.f, 0.f, 0.f};
  const float*  arow = X + (size_t)(m0 + r) * DD + ks * 256 + quad * 8;
  const __bf16* b0   = Wb + (size_t)(n0 + r) * DD + ks * 256 + quad * 8;
  const __bf16* b1   = b0 + 16 * DD;

#pragma unroll
  for (int kk = 0; kk < 256; kk += 32) {
    float4 a0 = *(const float4*)(arow + kk);
    float4 a1 = *(const float4*)(arow + kk + 4);
    bf16x8 af;
    af[0] = (__bf16)a0.x; af[1] = (__bf16)a0.y;
    af[2] = (__bf16)a0.z; af[3] = (__bf16)a0.w;
    af[4] = (__bf16)a1.x; af[5] = (__bf16)a1.y;
    af[6] = (__bf16)a1.z; af[7] = (__bf16)a1.w;
    bf16x8 bf0 = *(const bf16x8*)(b0 + kk);
    bf16x8 bf1 = *(const bf16x8*)(b1 + kk);
    acc0 = __builtin_amdgcn_mfma_f32_16x16x32_bf16(af, bf0, acc0, 0, 0, 0);
    acc1 = __builtin_amdgcn_mfma_f32_16x16x32_bf16(af, bf1, acc1, 0, 0, 0);
  }

  __shared__ float part[2][64][9];   // +1 pad: conflict-free combine
  if (ks == 1) {
#pragma unroll
    for (int i = 0; i < 4; ++i) {
      part[tw][lane][i]     = acc0[i];
      part[tw][lane][4 + i] = acc1[i];
    }
  }
  __syncthreads();
  if (ks == 0) {
#pragma unroll
    for (int i = 0; i < 4; ++i) {
      acc0[i] += part[tw][lane][i];
      acc1[i] += part[tw][lane][4 + i];
    }
    const int mrow = m0 + quad * 4;
    if (!is_k) {
#pragma unroll
      for (int i = 0; i < 4; ++i) {
        eqp[(size_t)(mrow + i) * HH + n0 + r] =
            __builtin_amdgcn_exp2f(acc0[i]);
        eqp[(size_t)(mrow + i) * HH + n0 + 16 + r] =
            __builtin_amdgcn_exp2f(acc1[i]);
      }
    } else {
      const int na = n0 + r, nb = n0 + 16 + r;
#pragma unroll
      for (int i = 0; i < 4; ++i) {
        const int m = mrow + i;
        ekf[((size_t)(m >> 4) * 64 + (na >> 2)) * 64 + (m & 15) * 4 + (na & 3)] =
            __builtin_amdgcn_exp2f(acc0[i]);
        ekf[((size_t)(m >> 4) * 64 + (nb >> 2)) * 64 + (m & 15) * 4 + (nb & 3)] =
            __builtin_amdgcn_exp2f(acc1[i]);
      }
    }
  }
}

// ---------------------------------------------------------------------------
// score (R12): VALU-execute-bound (R11 post-mortem: operand reads are ~4%
// of issue; 87% is the quad-term math). Cut 3.5 -> 3.0 VALU/h by 2-way
// reciprocal grouping: acc += n01*rcp(p01) + n23*rcp(p23) drops the
// 4-way cross-combine (N,P muls): 14 -> 12 VALU per 4h. Trans-pipe rcp
// doubles to 2/4h (16 cyc) but stays under VALU (24 cyc) -> still
// VALU-bound. Floor: 268M h x 3.0 ops / 78.6T lane-ops/s ~= 10.2 us.
//   out[b,q,k] = sumW + sum_h w2_h/u_h;  u = 1 + eq*ek;  w2 = -2*wv
// ek layout [m/16][hq(64)][m%16][4f32]: 16 consecutive lanes read one
// contiguous 256B segment per load; all chunk loads imm-offset batched.
// Grid (2,128,4) x 256 thr = 4 blocks/CU -> 16 waves/CU (4/SIMD).
// ---------------------------------------------------------------------------
__device__ __forceinline__ float quad_term(
    float4 ek, float4 e, float4 w, float acc)
{
  float u0 = fmaf(e.x, ek.x, 1.0f);
  float u1 = fmaf(e.y, ek.y, 1.0f);
  float u2 = fmaf(e.z, ek.z, 1.0f);
  float u3 = fmaf(e.w, ek.w, 1.0f);
  float p01 = u0 * u1;
  float p23 = u2 * u3;
  float n01 = fmaf(w.y, u0, w.x * u1);
  float n23 = fmaf(w.w, u2, w.z * u3);
  acc = fmaf(n01, __builtin_amdgcn_rcpf(p01), acc);
  acc = fmaf(n23, __builtin_amdgcn_rcpf(p23), acc);
  return acc;
}

__global__ __launch_bounds__(256, 4) void score_kernel(
    const float* __restrict__ eqp, const float4* __restrict__ ekf,
    const float* __restrict__ wv2, const float* __restrict__ sumWp,
    float* __restrict__ out)
{
  const int t  = threadIdx.x;          // k lane 0..255
  const int b  = blockIdx.z;
  const int k  = blockIdx.x * 256 + t;
  const int q0 = blockIdx.y * 4;

  // Block-uniform row bases -> scalar loads through K$ (5 KB footprint).
  const float* __restrict__ e0p = eqp + (size_t)(b * 512 + q0) * HH;
  const float* __restrict__ e1p = e0p + HH;
  const float* __restrict__ e2p = e0p + 2 * HH;
  const float* __restrict__ e3p = e0p + 3 * HH;

  const int m = b * 512 + k;           // global key row in [0,2048)
  const float4* __restrict__ kp =
      ekf + (size_t)(m >> 4) * 1024 + (m & 15);   // float4 units

  float acc0 = 0.f, acc1 = 0.f, acc2 = 0.f, acc3 = 0.f;

  for (int c = 0; c < 16; ++c) {       // 16 chunks x 4 hq = 64 hq
    float4 kb[4];
#pragma unroll
    for (int i = 0; i < 4; ++i)        // imm offsets 0/256/512/768 B
      kb[i] = kp[i * 16];
    kp += 64;                          // next chunk: +1KB
#pragma unroll
    for (int i = 0; i < 4; ++i) {
      const int h4 = c * 16 + i * 4;   // uniform (SALU) arithmetic
      float4 w4 = *(const float4*)(wv2 + h4);
      acc0 = quad_term(kb[i], *(const float4*)(e0p + h4), w4, acc0);
      acc1 = quad_term(kb[i], *(const float4*)(e1p + h4), w4, acc1);
      acc2 = quad_term(kb[i], *(const float4*)(e2p + h4), w4, acc2);
      acc3 = quad_term(kb[i], *(const float4*)(e3p + h4), w4, acc3);
    }
  }

  const float sumW = *sumWp;
  float* obase = out + (size_t)(b * 512 + q0) * 512 + blockIdx.x * 256 + t;
  obase[0]    = sumW + acc0;
  obase[512]  = sumW + acc1;
  obase[1024] = sumW + acc2;
  obase[1536] = sumW + acc3;
}

// ---------------------------------------------------------------------------
extern "C" void kernel_launch(void* const* d_in, const int* in_sizes, int n_in,
                              void* d_out, int out_size, void* d_ws, size_t ws_size,
                              hipStream_t stream) {
  (void)in_sizes; (void)n_in; (void)out_size; (void)ws_size;
  const float* queries = (const float*)d_in[0];
  const float* Keys    = (const float*)d_in[1];
  const float* Wq      = (const float*)d_in[2];
  const float* Wk      = (const float*)d_in[3];
  const float* wv      = (const float*)d_in[4];
  float* out = (float*)d_out;

  // ws layout (~10 MB of the 256 MB workspace):
  //   [0, 512K)      Wt   bf16 [2][256][512]
  //   [512K, +1K)    wv2  f32 [256]  (= -2*wv)
  //   [513K, +4)     sumW
  //   [5M, 7M)       eq   f32  [2048][256]
  //   [8M, 10M)      ekf  f32  [m/16][64][16][4]
  char* ws = (char*)d_ws;
  __bf16* Wt    = (__bf16*)ws;
  float*  wv2   = (float*)(ws + (512 << 10));
  float*  sumWp = (float*)(ws + (513 << 10));
  float*  eqp   = (float*)(ws + (5ull << 20));
  float*  ekf   = (float*)(ws + (8ull << 20));

  prep_kernel<<<dim3(257), 256, 0, stream>>>(Wq, Wk, wv, Wt, wv2, sumWp);
  proj_kernel<<<dim3(64, 8, 2), 256, 0, stream>>>(queries, Keys, Wt, eqp, ekf);
  score_kernel<<<dim3(2, 128, 4), 256, 0, stream>>>(
      eqp, (const float4*)ekf, wv2, sumWp, out);
}

// Round 3
// 107.607 us; speedup vs baseline: 1.0428x; 1.0428x over previous
//
#include <hip/hip_runtime.h>
#include <hip/hip_bf16.h>

// B=4, Q=K=512, D=512, H=256
#define HH 256
#define DD 512
#define MM 2048                       // B*Q == B*K flattened rows
#define CSCALE 2.8853900817779268f    // 2*log2(e), folded into W (linear)

typedef __bf16 bf16x8 __attribute__((ext_vector_type(8)));
typedef float floatx4 __attribute__((ext_vector_type(4)));
typedef float floatx2 __attribute__((ext_vector_type(2)));

// h-permutation (R13): within each 8-h group, store order [h0,h4,h1,h5,
// h2,h6,h3,h7] so score's packed-f32 pairs (pk lane0 = subgroup A h0..h3,
// pk lane1 = subgroup B h4..h7) read contiguously. Applied consistently
// to wv2, eq, ek -> any h-permutation is correctness-neutral (sum over h).
__device__ __forceinline__ int hperm(int h) {
  return (h & ~7) | (((h & 3) << 1) | ((h >> 2) & 1));
}

// ---------------------------------------------------------------------------
// prep: blocks 0..255: transpose+scale Wq,Wk -> Wt[2][256][512] bf16
//       block 256:     wv2[hperm] = -2*wv, sumW = sum(wv)
// ---------------------------------------------------------------------------
__global__ __launch_bounds__(256) void prep_kernel(
    const float* __restrict__ Wq, const float* __restrict__ Wk,
    const float* __restrict__ wv,
    __bf16* __restrict__ Wt, float* __restrict__ wv2, float* __restrict__ sumWp)
{
  const int bx = blockIdx.x;
  if (bx < 256) {
    const int mat  = bx >> 7;
    const int tile = bx & 127;
    const int kt = tile & 15;    // 512/32 k-tiles
    const int nt = tile >> 4;    // 256/32 n-tiles
    const float* __restrict__ W = mat ? Wk : Wq;
    __bf16* __restrict__ Wo = Wt + (size_t)mat * HH * DD;
    __shared__ float lds[32][33];
    const int i = threadIdx.x >> 5;   // 0..7
    const int j = threadIdx.x & 31;   // 0..31
    const int k0 = kt * 32, n0 = nt * 32;
#pragma unroll
    for (int p = 0; p < 4; ++p)
      lds[i + p * 8][j] = W[(k0 + i + p * 8) * HH + n0 + j];
    __syncthreads();
#pragma unroll
    for (int p = 0; p < 4; ++p) {
      const int n = i + p * 8;
      Wo[(n0 + n) * DD + k0 + j] = (__bf16)(lds[j][n] * CSCALE);
    }
  } else {
    __shared__ float red[256];
    const int t = threadIdx.x;
    float w = wv[t];
    wv2[hperm(t)] = -2.0f * w;
    red[t] = w;
    __syncthreads();
    for (int s = 128; s > 0; s >>= 1) {
      if (t < s) red[t] += red[t + s];
      __syncthreads();
    }
    if (t == 0) *sumWp = red[0];
  }
}

// ---------------------------------------------------------------------------
// proj: A-operand loaded f32 directly from queries/keys (RNE cast to bf16
// in-register, numerics identical to staged conversion). Epilogue applies
// hperm to the h-column of both outputs:
//   z==0: queries -> eq = exp2(qc) f32  [2048][256]   (columns hperm'd)
//   z==1: keys    -> ek = exp2(kc) f32  [m/16][hq'(64)][m%16][4] (hperm'd)
// Fragment layouts (HW-verified rounds 1-9):
//   A: lane A[m=lane&15][k=(lane>>4)*8+j]; B: B[k=(lane>>4)*8+j][n=lane&15]
//   D: reg i -> row=(lane>>4)*4+i, col=lane&15
// ---------------------------------------------------------------------------
__global__ __launch_bounds__(256, 4) void proj_kernel(
    const float* __restrict__ queries, const float* __restrict__ keys,
    const __bf16* __restrict__ Wt,
    float* __restrict__ eqp, float* __restrict__ ekf)
{
  const int w    = threadIdx.x >> 6;
  const int lane = threadIdx.x & 63;
  const int quad = lane >> 4;
  const int r    = lane & 15;
  const int tw = w & 1;        // which 16-row tile
  const int ks = w >> 1;       // which K half
  const bool is_k = (blockIdx.z != 0);
  const float* __restrict__ X  = is_k ? keys : queries;
  const __bf16* __restrict__ Wb = Wt + (is_k ? (size_t)HH * DD : 0);

  const int m0 = blockIdx.x * 32 + tw * 16;
  const int n0 = blockIdx.y * 32;

  floatx4 acc0 = {0.f, 0.f, 0.f, 0.f};
  floatx4 acc1 = {0.f, 0.f, 0.f, 0.f};
  const float*  arow = X + (size_t)(m0 + r) * DD + ks * 256 + quad * 8;
  const __bf16* b0   = Wb + (size_t)(n0 + r) * DD + ks * 256 + quad * 8;
  const __bf16* b1   = b0 + 16 * DD;

#pragma unroll
  for (int kk = 0; kk < 256; kk += 32) {
    float4 a0 = *(const float4*)(arow + kk);
    float4 a1 = *(const float4*)(arow + kk + 4);
    bf16x8 af;
    af[0] = (__bf16)a0.x; af[1] = (__bf16)a0.y;
    af[2] = (__bf16)a0.z; af[3] = (__bf16)a0.w;
    af[4] = (__bf16)a1.x; af[5] = (__bf16)a1.y;
    af[6] = (__bf16)a1.z; af[7] = (__bf16)a1.w;
    bf16x8 bf0 = *(const bf16x8*)(b0 + kk);
    bf16x8 bf1 = *(const bf16x8*)(b1 + kk);
    acc0 = __builtin_amdgcn_mfma_f32_16x16x32_bf16(af, bf0, acc0, 0, 0, 0);
    acc1 = __builtin_amdgcn_mfma_f32_16x16x32_bf16(af, bf1, acc1, 0, 0, 0);
  }

  __shared__ float part[2][64][9];   // +1 pad: conflict-free combine
  if (ks == 1) {
#pragma unroll
    for (int i = 0; i < 4; ++i) {
      part[tw][lane][i]     = acc0[i];
      part[tw][lane][4 + i] = acc1[i];
    }
  }
  __syncthreads();
  if (ks == 0) {
#pragma unroll
    for (int i = 0; i < 4; ++i) {
      acc0[i] += part[tw][lane][i];
      acc1[i] += part[tw][lane][4 + i];
    }
    const int mrow = m0 + quad * 4;
    const int sa = hperm(n0 + r), sb = hperm(n0 + 16 + r);
    if (!is_k) {
#pragma unroll
      for (int i = 0; i < 4; ++i) {
        eqp[(size_t)(mrow + i) * HH + sa] = __builtin_amdgcn_exp2f(acc0[i]);
        eqp[(size_t)(mrow + i) * HH + sb] = __builtin_amdgcn_exp2f(acc1[i]);
      }
    } else {
#pragma unroll
      for (int i = 0; i < 4; ++i) {
        const int m = mrow + i;
        ekf[((size_t)(m >> 4) * 64 + (sa >> 2)) * 64 + (m & 15) * 4 + (sa & 3)] =
            __builtin_amdgcn_exp2f(acc0[i]);
        ekf[((size_t)(m >> 4) * 64 + (sb >> 2)) * 64 + (m & 15) * 4 + (sb & 3)] =
            __builtin_amdgcn_exp2f(acc1[i]);
      }
    }
  }
}

// ---------------------------------------------------------------------------
// score (R13): packed-FP32 8-way grouping. Two 4-h subgroups (A=h0..3,
// B=h4..7 of each 8-group) live in the two v_pk_* lanes; producers stored
// h interleaved [h0,h4,h1,h5,h2,h6,h3,h7] so all pairs load contiguously.
// Per 8h: 13 pk (u:4, p:2, n:4, Np:2, Pp:1) + N8/P8 (3 scalar) + rcp
// (quarter-rate trans = 4 VALU-equiv, R12 lesson) + acc = 21 equiv
// vs R11's 36 -> 42% issue-pressure cut. Floor ~9.0 us.
//   out[b,q,k] = sumW + sum_groups N8 * rcp(P8);  u = 1 + eq*ek
//   n01 = w'0*u1 + w'1*u0; N4 = n01*p23+n23*p01; P4 = p01*p23;
//   N8 = NA*PB + NB*PA; P8 = PA*PB   (w' = -2*wv, exact tanh algebra)
// Overflow: P8 = prod of 8 u needs sum(2x) > 88 ~ 11 sigma -> never.
// Grid (2,128,4) x 256 thr = 4 blocks/CU -> 16 waves/CU (4/SIMD).
// ---------------------------------------------------------------------------
__device__ __forceinline__ float octo_term(
    floatx4 kA, floatx4 kB, floatx4 eA, floatx4 eB,
    floatx4 wA, floatx4 wB, float acc)
{
  const floatx2 one = {1.0f, 1.0f};
#define LO2(v) __builtin_shufflevector(v, v, 0, 1)
#define HI2(v) __builtin_shufflevector(v, v, 2, 3)
  floatx2 u0 = __builtin_elementwise_fma(LO2(eA), LO2(kA), one);  // {h0,h4}
  floatx2 u1 = __builtin_elementwise_fma(HI2(eA), HI2(kA), one);  // {h1,h5}
  floatx2 u2 = __builtin_elementwise_fma(LO2(eB), LO2(kB), one);  // {h2,h6}
  floatx2 u3 = __builtin_elementwise_fma(HI2(eB), HI2(kB), one);  // {h3,h7}
  floatx2 p01 = u0 * u1;                                          // {A,B}
  floatx2 p23 = u2 * u3;
  floatx2 n01 = __builtin_elementwise_fma(LO2(wA), u1, HI2(wA) * u0);
  floatx2 n23 = __builtin_elementwise_fma(LO2(wB), u3, HI2(wB) * u2);
  floatx2 Np  = __builtin_elementwise_fma(n23, p01, n01 * p23);   // {NA,NB}
  floatx2 Pp  = p01 * p23;                                        // {PA,PB}
  float N8 = fmaf(Np.x, Pp.y, Np.y * Pp.x);
  float P8 = Pp.x * Pp.y;
  return fmaf(N8, __builtin_amdgcn_rcpf(P8), acc);
#undef LO2
#undef HI2
}

__global__ __launch_bounds__(256, 4) void score_kernel(
    const float* __restrict__ eqp, const floatx4* __restrict__ ekf,
    const float* __restrict__ wv2, const float* __restrict__ sumWp,
    float* __restrict__ out)
{
  const int t  = threadIdx.x;          // k lane 0..255
  const int b  = blockIdx.z;
  const int k  = blockIdx.x * 256 + t;
  const int q0 = blockIdx.y * 4;

  // Block-uniform row bases -> scalar K$ loads (5 KB footprint).
  const float* __restrict__ e0p = eqp + (size_t)(b * 512 + q0) * HH;
  const float* __restrict__ e1p = e0p + HH;
  const float* __restrict__ e2p = e0p + 2 * HH;
  const float* __restrict__ e3p = e0p + 3 * HH;

  const int m = b * 512 + k;           // global key row in [0,2048)
  const floatx4* __restrict__ kp =
      ekf + (size_t)(m >> 4) * 1024 + (m & 15);   // float4 units

  float acc0 = 0.f, acc1 = 0.f, acc2 = 0.f, acc3 = 0.f;

  for (int c = 0; c < 16; ++c) {       // 16 chunks x 16 h = 256 h
    floatx4 k0 = kp[0];                // imm offsets 0/256/512/768 B
    floatx4 k1 = kp[16];
    floatx4 k2 = kp[32];
    floatx4 k3 = kp[48];
    kp += 64;                          // next chunk: +1KB
    const int h0 = c * 16;             // uniform (SALU) arithmetic
    floatx4 w0 = *(const floatx4*)(wv2 + h0);
    floatx4 w1 = *(const floatx4*)(wv2 + h0 + 4);
    floatx4 w2 = *(const floatx4*)(wv2 + h0 + 8);
    floatx4 w3 = *(const floatx4*)(wv2 + h0 + 12);

#define ROW(accv, ep)                                                     \
    accv = octo_term(k0, k1, *(const floatx4*)(ep + h0),                  \
                     *(const floatx4*)(ep + h0 + 4),  w0, w1, accv);      \
    accv = octo_term(k2, k3, *(const floatx4*)(ep + h0 + 8),              \
                     *(const floatx4*)(ep + h0 + 12), w2, w3, accv);
    ROW(acc0, e0p)
    ROW(acc1, e1p)
    ROW(acc2, e2p)
    ROW(acc3, e3p)
#undef ROW
  }

  const float sumW = *sumWp;
  float* obase = out + (size_t)(b * 512 + q0) * 512 + blockIdx.x * 256 + t;
  obase[0]    = sumW + acc0;
  obase[512]  = sumW + acc1;
  obase[1024] = sumW + acc2;
  obase[1536] = sumW + acc3;
}

// ---------------------------------------------------------------------------
extern "C" void kernel_launch(void* const* d_in, const int* in_sizes, int n_in,
                              void* d_out, int out_size, void* d_ws, size_t ws_size,
                              hipStream_t stream) {
  (void)in_sizes; (void)n_in; (void)out_size; (void)ws_size;
  const float* queries = (const float*)d_in[0];
  const float* Keys    = (const float*)d_in[1];
  const float* Wq      = (const float*)d_in[2];
  const float* Wk      = (const float*)d_in[3];
  const float* wv      = (const float*)d_in[4];
  float* out = (float*)d_out;

  // ws layout (~10 MB of the 256 MB workspace):
  //   [0, 512K)      Wt   bf16 [2][256][512]
  //   [512K, +1K)    wv2  f32 [256]  (= -2*wv, hperm'd)
  //   [513K, +4)     sumW
  //   [5M, 7M)       eq   f32  [2048][256]        (h columns hperm'd)
  //   [8M, 10M)      ekf  f32  [m/16][64][16][4]  (h slots hperm'd)
  char* ws = (char*)d_ws;
  __bf16* Wt    = (__bf16*)ws;
  float*  wv2   = (float*)(ws + (512 << 10));
  float*  sumWp = (float*)(ws + (513 << 10));
  float*  eqp   = (float*)(ws + (5ull << 20));
  float*  ekf   = (float*)(ws + (8ull << 20));

  prep_kernel<<<dim3(257), 256, 0, stream>>>(Wq, Wk, wv, Wt, wv2, sumWp);
  proj_kernel<<<dim3(64, 8, 2), 256, 0, stream>>>(queries, Keys, Wt, eqp, ekf);
  score_kernel<<<dim3(2, 128, 4), 256, 0, stream>>>(
      eqp, (const floatx4*)ekf, wv2, sumWp, out);
}